// Round 4
// baseline (652.333 us; speedup 1.0000x reference)
//
#include <hip/hip_runtime.h>
#include <math.h>

#define NB1 1024          // blocks in pass 1
#define TPB 256           // threads per block
#define WPB (TPB / 64)                          // 4 waves per block
#define NWAVE (NB1 * WPB)                       // 4096 waves total
#define ROWS_PER_ITER 16                        // rows per wave per iteration
#define STRIDE (NWAVE * ROWS_PER_ITER)          // 65536-row grid stride
#define NLEADER (WPB * 2)                       // 8 distinct top-5 lists per block
#define NBCAND (NLEADER * 5)                    // 40 block-local candidates
#define NCAND (NB1 * 5)                         // 5120 global candidates

constexpr float EPS = 1e-6f;

typedef float f32x4 __attribute__((ext_vector_type(4)));

__device__ __forceinline__ bool better(float v, int i, float bv, int bi) {
    // strictly-greater wins; on exact tie, lower row index wins (jax top_k order)
    return (v > bv) || (v == bv && i < bi);
}

// pass-1 insert: rows arrive in increasing index order per lane, so a value
// equal to tv[4] has a larger index and correctly loses -> cheap reject exact
__device__ __forceinline__ void insert5_asc(float nv, int ni, float tv[5], int ti[5]) {
    if (nv > tv[4]) {
        #pragma unroll
        for (int j = 0; j < 5; j++) {           // bubble-insert, keeps sorted desc
            bool b = better(nv, ni, tv[j], ti[j]);
            float ov = tv[j]; int oi = ti[j];
            if (b) { tv[j] = nv; ti[j] = ni; nv = ov; ni = oi; }
        }
    }
}

// order-agnostic insert (final pass: candidates arrive in arbitrary index order)
__device__ __forceinline__ void insert5_any(float nv, int ni, float tv[5], int ti[5]) {
    if (better(nv, ni, tv[4], ti[4])) {
        #pragma unroll
        for (int j = 0; j < 5; j++) {
            bool b = better(nv, ni, tv[j], ti[j]);
            float ov = tv[j]; int oi = ti[j];
            if (b) { tv[j] = nv; ti[j] = ni; nv = ov; ni = oi; }
        }
    }
}

__global__ __launch_bounds__(TPB) void sim_block_topk(
    const float* __restrict__ W, const int* __restrict__ qidx,
    int V, float* __restrict__ bv, int* __restrict__ bi)
{
    const int tid   = threadIdx.x;
    const int lane  = tid & 63;
    const int wave  = tid >> 6;
    const int hi    = lane >> 5;                // 0: even row of pair, 1: odd row
    const int hlane = lane & 31;                // position within 32-lane half
    const int waveGlobal = blockIdx.x * WPB + wave;

    const int q = qidx[0];

    // each lane owns q floats [hlane*4, hlane*4+4): one float4, same fragment
    // for every row since in-row position is fixed by hlane
    const f32x4* Q4 = (const f32x4*)(W + (size_t)q * 128);
    const f32x4 qv = Q4[hlane];

    float qn2 = qv[0]*qv[0] + qv[1]*qv[1] + qv[2]*qv[2] + qv[3]*qv[3];
    #pragma unroll
    for (int m = 1; m <= 16; m <<= 1) qn2 += __shfl_xor(qn2, m);
    const float qn = sqrtf(qn2);

    float tv[5]; int ti[5];
    #pragma unroll
    for (int j = 0; j < 5; j++) { tv[j] = -INFINITY; ti[j] = 0x7fffffff; }

    // wave-linear loads: each dwordx4 instruction reads a CONTIGUOUS aligned
    // 1 KB (64 lanes x 16 B) = one row pair. 8 instructions = 16 rows / iter
    // (8 KB contiguous in flight per wave). V % 16 == 0 (V = 1e6) -> no tail.
    for (int chunk = waveGlobal * ROWS_PER_ITER; chunk < V; chunk += STRIDE) {
        const f32x4* P4 = (const f32x4*)(W + (size_t)chunk * 128);
        f32x4 a[8];
        #pragma unroll
        for (int p = 0; p < 8; p++)
            a[p] = __builtin_nontemporal_load(P4 + p * 64 + lane);

        float dt[8], nr[8];
        #pragma unroll
        for (int p = 0; p < 8; p++) {
            dt[p] = a[p][0]*qv[0] + a[p][1]*qv[1] + a[p][2]*qv[2] + a[p][3]*qv[3];
            nr[p] = a[p][0]*a[p][0] + a[p][1]*a[p][1] + a[p][2]*a[p][2] + a[p][3]*a[p][3];
        }
        // 5-stage butterfly within each 32-lane half; 16 independent shuffles
        // per stage keep the LDS pipe saturated
        #pragma unroll
        for (int m = 1; m <= 16; m <<= 1) {
            #pragma unroll
            for (int p = 0; p < 8; p++) dt[p] += __shfl_xor(dt[p], m);
            #pragma unroll
            for (int p = 0; p < 8; p++) nr[p] += __shfl_xor(nr[p], m);
        }
        #pragma unroll
        for (int p = 0; p < 8; p++) {
            float sim = dt[p] / fmaxf(qn * sqrtf(nr[p]), EPS);
            insert5_asc(sim, chunk + 2 * p + hi, tv, ti);
        }
    }

    // ---- block combine: 8 leader lists x 5 -> block top-5 ----
    __shared__ float s_v[NBCAND];
    __shared__ int   s_i[NBCAND];
    __shared__ float sw_v[WPB];
    __shared__ int   sw_i[WPB], sw_p[WPB];

    if (hlane == 0) {                           // lanes 0 and 32 of each wave
        const int leader = wave * 2 + hi;
        #pragma unroll
        for (int j = 0; j < 5; j++) { s_v[leader*5 + j] = tv[j]; s_i[leader*5 + j] = ti[j]; }
    }
    __syncthreads();

    for (int k = 0; k < 5; k++) {
        float v = -INFINITY; int i = 0x7fffffff; int p = 0;
        for (int e = tid; e < NBCAND; e += TPB) {
            if (better(s_v[e], s_i[e], v, i)) { v = s_v[e]; i = s_i[e]; p = e; }
        }
        #pragma unroll
        for (int m = 32; m >= 1; m >>= 1) {
            float ov = __shfl_xor(v, m);
            int   oi = __shfl_xor(i, m);
            int   op = __shfl_xor(p, m);
            if (better(ov, oi, v, i)) { v = ov; i = oi; p = op; }
        }
        if (lane == 0) { sw_v[wave] = v; sw_i[wave] = i; sw_p[wave] = p; }
        __syncthreads();
        if (tid == 0) {
            for (int w = 1; w < WPB; w++)
                if (better(sw_v[w], sw_i[w], sw_v[0], sw_i[0])) {
                    sw_v[0] = sw_v[w]; sw_i[0] = sw_i[w]; sw_p[0] = sw_p[w];
                }
            bv[blockIdx.x*5 + k] = sw_v[0];
            bi[blockIdx.x*5 + k] = sw_i[0];
            s_v[sw_p[0]] = -INFINITY;
        }
        __syncthreads();
    }
}

__global__ __launch_bounds__(256) void final_topk(
    const float* __restrict__ bv, const int* __restrict__ bi,
    float* __restrict__ out)
{
    // per-thread register top-5 over 20 candidates, then 5-round argmax
    __shared__ float s_v[256 * 5];
    __shared__ int   s_i[256 * 5];
    __shared__ float sw_v[4];
    __shared__ int   sw_i[4], sw_p[4];

    const int tid  = threadIdx.x;
    const int lane = tid & 63;

    float tv[5]; int ti[5];
    #pragma unroll
    for (int j = 0; j < 5; j++) { tv[j] = -INFINITY; ti[j] = 0x7fffffff; }

    for (int e = tid; e < NCAND; e += 256)
        insert5_any(bv[e], bi[e], tv, ti);

    #pragma unroll
    for (int j = 0; j < 5; j++) { s_v[tid*5 + j] = tv[j]; s_i[tid*5 + j] = ti[j]; }
    __syncthreads();

    for (int k = 0; k < 5; k++) {
        float v = -INFINITY; int i = 0x7fffffff; int p = 0;
        for (int e = tid; e < 256 * 5; e += 256) {
            if (better(s_v[e], s_i[e], v, i)) { v = s_v[e]; i = s_i[e]; p = e; }
        }
        #pragma unroll
        for (int m = 32; m >= 1; m >>= 1) {
            float ov = __shfl_xor(v, m);
            int   oi = __shfl_xor(i, m);
            int   op = __shfl_xor(p, m);
            if (better(ov, oi, v, i)) { v = ov; i = oi; p = op; }
        }
        if (lane == 0) { int w = tid >> 6; sw_v[w] = v; sw_i[w] = i; sw_p[w] = p; }
        __syncthreads();
        if (tid == 0) {
            for (int w = 1; w < 4; w++)
                if (better(sw_v[w], sw_i[w], sw_v[0], sw_i[0])) {
                    sw_v[0] = sw_v[w]; sw_i[0] = sw_i[w]; sw_p[0] = sw_p[w];
                }
            out[k]     = sw_v[0];
            out[5 + k] = (float)sw_i[0];
            s_v[sw_p[0]] = -INFINITY;
        }
        __syncthreads();
    }
}

extern "C" void kernel_launch(void* const* d_in, const int* in_sizes, int n_in,
                              void* d_out, int out_size, void* d_ws, size_t ws_size,
                              hipStream_t stream) {
    const float* W    = (const float*)d_in[0];
    const int*   qidx = (const int*)d_in[1];   // low word of int64 is correct (LE, V < 2^31)
    const int V = in_sizes[0] / 128;

    float* bv = (float*)d_ws;
    int*   bi = (int*)((char*)d_ws + (size_t)NB1 * 5 * sizeof(float));

    sim_block_topk<<<NB1, TPB, 0, stream>>>(W, qidx, V, bv, bi);
    final_topk<<<1, 256, 0, stream>>>(bv, bi, (float*)d_out);
}